// Round 16
// baseline (145.482 us; speedup 1.0000x reference)
//
#include <hip/hip_runtime.h>
#include <hip/hip_bf16.h>

typedef __attribute__((ext_vector_type(8))) short short8;
typedef __attribute__((ext_vector_type(4))) float f32x4;
typedef __attribute__((ext_vector_type(16))) float f32x16;
typedef __attribute__((ext_vector_type(4))) unsigned short u16x4;
typedef __attribute__((ext_vector_type(8))) unsigned short u16x8;
typedef __attribute__((ext_vector_type(4))) unsigned int u32x4;

__device__ __forceinline__ unsigned short f2b(float f) {
  __hip_bfloat16 h = __float2bfloat16(f);
  return __builtin_bit_cast(unsigned short, h);
}

__device__ __forceinline__ void gload_lds16(const void* g, void* l) {
  __builtin_amdgcn_global_load_lds(
      (const __attribute__((address_space(1))) unsigned int*)g,
      (__attribute__((address_space(3))) unsigned int*)l, 16, 0, 0);
}

__device__ __forceinline__ f32x16 mfma32(short8 a, short8 b, f32x16 c) {
  return __builtin_amdgcn_mfma_f32_32x32x16_bf16(a, b, c, 0, 0, 0);
}

__device__ __forceinline__ unsigned int cvtpk(float a, float b) {
  unsigned int r;
  asm("v_cvt_pk_bf16_f32 %0, %1, %2" : "=v"(r) : "v"(a), "v"(b));
  return r;
}

// ------- fused prepass: activations f32->bf16 + weight transpose/convert -----
struct PrepassParams {
  const float* sw;
  const float* se;
  unsigned short* dw;
  unsigned short* de;
  const float* w[6];
  unsigned short* wt[6];
};

__global__ __launch_bounds__(256) void prepass(PrepassParams p) {
  const int bx = blockIdx.x;
  const int tid = threadIdx.x;
  if (bx < 2304) {
    int i = bx * 256 + tid;
    const float* s;
    unsigned short* d;
    int j;
    if (i < 524288) {
      s = p.sw; d = p.dw; j = i;
    } else {
      s = p.se; d = p.de; j = i - 524288;
      if (j >= 65536) return;
    }
    const f32x4* sp = (const f32x4*)s;
    f32x4 a = sp[2 * j];
    f32x4 b = sp[2 * j + 1];
    u16x8 o;
    o[0] = f2b(a[0]); o[1] = f2b(a[1]); o[2] = f2b(a[2]); o[3] = f2b(a[3]);
    o[4] = f2b(b[0]); o[5] = f2b(b[1]); o[6] = f2b(b[2]); o[7] = f2b(b[3]);
    ((u16x8*)d)[j] = o;
  } else {
    __shared__ float t[32][33];
    const int idx = bx - 2304;
    const int z = idx >> 10;
    const int rem = idx & 1023;
    const int bxx = rem & 31;
    const int byy = rem >> 5;
    const float* W = p.w[z];
    unsigned short* Wt = p.wt[z];
    const int tx = tid & 31, ty = tid >> 5;
#pragma unroll
    for (int i = 0; i < 4; ++i)
      t[ty + 8 * i][tx] = W[(byy * 32 + ty + 8 * i) * 1024 + bxx * 32 + tx];
    __syncthreads();
#pragma unroll
    for (int i = 0; i < 4; ++i)
      Wt[(bxx * 32 + ty + 8 * i) * 1024 + byy * 32 + tx] = f2b(t[tx][ty + 8 * i]);
  }
}

// ---------------- merged batched projection GEMM ----------------
// Block remap: z (job) varies FASTEST in per-XCD dispatch order so the A-slab
// (256KB) is L2-reused across the 4 jobs before moving to the next row-tile.
struct GemmJob {
  const unsigned short* Wt;  // [1024][1024] bf16, n-major
  const float* bias;
  unsigned short* out;
  int S;
  int s_off;
  int sshift;
  int trans;  // 0: out[bh][s][64]; 1: out[bh][64][2304] (V transposed)
  float scale;
};
struct Gemm2Params {
  const unsigned short* Aw;
  const unsigned short* Ae;
  GemmJob job[8];
};

__global__ __launch_bounds__(256) void gemm_qkv(Gemm2Params p) {
  __shared__ unsigned short smem[16384];
  unsigned short* As = smem;
  unsigned short* Bs = smem + 8192;
  const int tid = threadIdx.x;
  const int w = tid >> 6, lane = tid & 63;
  const int c = lane & 15, g = lane >> 4;
  // L2-locality remap: wid = y + 36*z; consecutive wid per XCD -> z fastest
  const int wid = blockIdx.y + 36 * blockIdx.z;
  const int z = wid & 3;
  const int y = wid >> 2;
  const bool isword = y < 32;
  const GemmJob j = p.job[isword ? z : z + 4];
  const unsigned short* A = isword ? p.Aw : p.Ae;
  const long arow0 = (long)(isword ? y : y - 32) * 128;
  const unsigned short* B = j.Wt;
  const long brow0 = (long)blockIdx.x * 128;

  f32x4 acc[4][4] = {};

  for (int kt = 0; kt < 16; ++kt) {
    __syncthreads();
#pragma unroll
    for (int i = 0; i < 4; ++i) {
      int ch = i * 256 + tid;
      int row = ch >> 3;
      int k8 = ((ch & 7) ^ (row & 7)) << 3;
      const unsigned short* ga = A + (arow0 + row) * 1024 + kt * 64 + k8;
      const unsigned short* gb = B + (brow0 + row) * 1024 + kt * 64 + k8;
      gload_lds16(ga, As + (i * 256 + w * 64) * 8);
      gload_lds16(gb, Bs + (i * 256 + w * 64) * 8);
    }
    __syncthreads();
#pragma unroll
    for (int kf = 0; kf < 2; ++kf) {
      short8 av[4], bv[4];
#pragma unroll
      for (int mf = 0; mf < 4; ++mf) {
        int row = (w >> 1) * 64 + mf * 16 + c;
        int byte = (row * 128 + (kf * 32 + g * 8) * 2) ^ ((row & 7) << 4);
        av[mf] = *(const short8*)((const char*)As + byte);
      }
#pragma unroll
      for (int nf = 0; nf < 4; ++nf) {
        int row = (w & 1) * 64 + nf * 16 + c;
        int byte = (row * 128 + (kf * 32 + g * 8) * 2) ^ ((row & 7) << 4);
        bv[nf] = *(const short8*)((const char*)Bs + byte);
      }
      __builtin_amdgcn_s_setprio(1);
#pragma unroll
      for (int mf = 0; mf < 4; ++mf)
#pragma unroll
        for (int nf = 0; nf < 4; ++nf)
          acc[mf][nf] = __builtin_amdgcn_mfma_f32_16x16x32_bf16(av[mf], bv[nf],
                                                                acc[mf][nf], 0, 0, 0);
      __builtin_amdgcn_s_setprio(0);
    }
  }

  float biasv[4];
#pragma unroll
  for (int nf = 0; nf < 4; ++nf) {
    int n = (int)brow0 + (w & 1) * 64 + nf * 16 + c;
    biasv[nf] = j.bias[n];
  }
  const int smask = (1 << j.sshift) - 1;
  __syncthreads();

  if (j.trans) {
#pragma unroll
    for (int mf = 0; mf < 4; ++mf) {
      int m0 = (w >> 1) * 64 + mf * 16 + g * 4;
#pragma unroll
      for (int nf = 0; nf < 4; ++nf) {
        int n = (w & 1) * 64 + nf * 16 + c;
        u16x4 pv;
#pragma unroll
        for (int r = 0; r < 4; ++r)
          pv[r] = f2b((acc[mf][nf][r] + biasv[nf]) * j.scale);
        int byte = (n * 256 + m0 * 2) ^ ((n & 7) << 4);
        *(u16x4*)((char*)smem + byte) = pv;
      }
    }
    __syncthreads();
#pragma unroll
    for (int i = 0; i < 8; ++i) {
      int ch = i * 256 + tid;
      int nr = ch >> 4, sl = ch & 15;
      int byte = (nr * 256 + sl * 16) ^ ((nr & 7) << 4);
      u16x8 v = *(const u16x8*)((const char*)smem + byte);
      int n = (int)brow0 + nr;
      int hh = n >> 6, dd = n & 63;
      int m = (int)arow0 + sl * 8;
      int b_ = m >> j.sshift;
      int s = (m & smask) + j.s_off;
      *(u16x8*)(j.out + (((long)b_ * 16 + hh) * 64 + dd) * 2304 + s) = v;
    }
  } else {
#pragma unroll
    for (int mf = 0; mf < 4; ++mf) {
#pragma unroll
      for (int r = 0; r < 4; ++r) {
        int m = (w >> 1) * 64 + mf * 16 + g * 4 + r;
#pragma unroll
        for (int nf = 0; nf < 4; ++nf) {
          int n = (w & 1) * 64 + nf * 16 + c;
          unsigned short hv = f2b((acc[mf][nf][r] + biasv[nf]) * j.scale);
          int byte = (m * 256 + n * 2) ^ ((m & 7) << 4);
          *(unsigned short*)((char*)smem + byte) = hv;
        }
      }
    }
    __syncthreads();
#pragma unroll
    for (int i = 0; i < 8; ++i) {
      int ch = i * 256 + tid;
      int mr = ch >> 4, sl = ch & 15;
      int byte = (mr * 256 + sl * 16) ^ ((mr & 7) << 4);
      u16x8 v = *(const u16x8*)((const char*)smem + byte);
      int m = (int)arow0 + mr;
      int b_ = m >> j.sshift;
      int s = (m & smask) + j.s_off;
      int n = (int)brow0 + sl * 8;
      int hh = n >> 6, dd = n & 63;
      *(u16x8*)(j.out + (((long)b_ * 16 + hh) * j.S + s) * 64 + dd) = v;
    }
  }
}

// ---------------- flash attention (key-split x3, counted-vmcnt pipeline) -----
// 1728 blocks (XCD-grouped), 4 waves x 32 q-rows, part = third of the key range
// (12 x 64-key tiles). P = exp2(st) unnormalized; scale cancels in merge.
__global__ __launch_bounds__(256) void attn_kernel(
    const unsigned short* __restrict__ qw2w, const unsigned short* __restrict__ qw2e,
    const unsigned short* __restrict__ qe2w, const unsigned short* __restrict__ qe2e,
    const unsigned short* __restrict__ Kg, const unsigned short* __restrict__ Vtg,
    float* __restrict__ po0, float* __restrict__ po1, float* __restrict__ po2,
    float* __restrict__ lbuf) {
  __shared__ unsigned short smem[16384];  // 32 KiB: K dbuf [0,8KB), Vt dbuf [16KB,32KB)

  const int tid = threadIdx.x;
  const int w = tid >> 6, lane = tid & 63;
  const int l31 = lane & 31, hf = lane >> 5;

  // XCD-grouped bijective remap: 1728 = 8 * 216; work = hb*54 + tile*3 + part
  const int flat = blockIdx.x;
  const int work = (flat & 7) * 216 + (flat >> 3);
  const int part = work % 3;
  const int tile = (work % 54) / 3;
  const int hb = work / 54;
  const int head = hb & 15, b = hb >> 4;

  const bool isw = tile < 16;
  const int Sq = isw ? 2048 : 256;
  const int q0 = (isw ? tile : tile - 16) * 128 + w * 32;
  const int bh = b * 16 + head;
  const unsigned short* Qa =
      (isw ? qw2w : qe2w) + ((long)bh * Sq + q0 + l31) * 64 + hf * 8;
  const unsigned short* Qb =
      (isw ? qw2e : qe2e) + ((long)bh * Sq + q0 + l31) * 64 + hf * 8;
  const unsigned short* Kb = Kg + (long)bh * 2304 * 64;
  const unsigned short* Vtb = Vtg + (long)bh * 64 * 2304;

  short8 qcur[4];
#pragma unroll
  for (int kf = 0; kf < 4; ++kf) qcur[kf] = *(const short8*)(Qa + kf * 16);

  f32x16 o[2] = {};
  float lrun = 0.f;

  auto stage = [&](int t, int bufi) {
    const unsigned short* Kt = Kb + t * 4096;
    unsigned short* Klp = smem + bufi * 4096;
    unsigned short* Vlp = smem + 8192 + bufi * 4096;
#pragma unroll
    for (int i = 0; i < 2; ++i) {
      int ch = i * 256 + tid;
      int row = ch >> 3, c8 = ch & 7;
      int col = (c8 ^ (row & 7)) << 3;
      gload_lds16(Kt + row * 64 + col, Klp + (i * 256 + (tid & 192)) * 8);
      gload_lds16(Vtb + row * 2304 + t * 64 + col, Vlp + (i * 256 + (tid & 192)) * 8);
    }
  };

  const int t0 = part * 12, t1 = t0 + 12;
  stage(t0, 0);
  int cur = 0;

  for (int t = t0; t < t1; ++t) {
    if (t == 32) {  // entity-key region: switch to the *2e query
#pragma unroll
      for (int kf = 0; kf < 4; ++kf) qcur[kf] = *(const short8*)(Qb + kf * 16);
    }
    if (t + 1 < t1) {
      stage(t + 1, cur ^ 1);
      asm volatile("s_waitcnt vmcnt(4)" ::: "memory");
    } else {
      asm volatile("s_waitcnt vmcnt(0)" ::: "memory");
    }
    __builtin_amdgcn_sched_barrier(0);
    __builtin_amdgcn_s_barrier();

    const char* Kbase = (const char*)(smem + cur * 4096);
    const char* Vbase = (const char*)(smem + 8192 + cur * 4096);

    // QK^T: ST[key][q], 2 key-groups of 32
    f32x16 st[2] = {};
#pragma unroll
    for (int kg = 0; kg < 2; ++kg) {
      int row = kg * 32 + l31;
      int rb = (row * 128) | (hf * 16);
      int sw = (row & 7) << 4;
      short8 kfr[4];
#pragma unroll
      for (int kf = 0; kf < 4; ++kf)
        kfr[kf] = *(const short8*)(Kbase + ((rb + kf * 32) ^ sw));
      __builtin_amdgcn_s_setprio(1);
#pragma unroll
      for (int kf = 0; kf < 4; ++kf) st[kg] = mfma32(kfr[kf], qcur[kf], st[kg]);
      __builtin_amdgcn_s_setprio(0);
    }

    // softmax: P = exp2(st), no max subtraction (scale cancels in merge).
    float s0 = 0.f, s1 = 0.f, s2 = 0.f, s3 = 0.f;
#pragma unroll
    for (int kg = 0; kg < 2; ++kg) {
#pragma unroll
      for (int r = 0; r < 16; r += 4) {
        float p0 = __builtin_amdgcn_exp2f(st[kg][r + 0]);
        float p1 = __builtin_amdgcn_exp2f(st[kg][r + 1]);
        float p2 = __builtin_amdgcn_exp2f(st[kg][r + 2]);
        float p3 = __builtin_amdgcn_exp2f(st[kg][r + 3]);
        st[kg][r + 0] = p0; st[kg][r + 1] = p1;
        st[kg][r + 2] = p2; st[kg][r + 3] = p3;
        s0 += p0; s1 += p1; s2 += p2; s3 += p3;
      }
    }
    lrun += (s0 + s1) + (s2 + s3);

    // P -> bf16 B-frags in-register (cvt_pk + permlane32_swap), PV accumulate
#pragma unroll
    for (int kg = 0; kg < 2; ++kg)
#pragma unroll
      for (int hs = 0; hs < 2; ++hs) {
        const int rbase = hs * 8;
        unsigned int a0 = cvtpk(st[kg][rbase + 0], st[kg][rbase + 1]);
        unsigned int a1 = cvtpk(st[kg][rbase + 2], st[kg][rbase + 3]);
        unsigned int b0 = cvtpk(st[kg][rbase + 4], st[kg][rbase + 5]);
        unsigned int b1 = cvtpk(st[kg][rbase + 6], st[kg][rbase + 7]);
        asm("v_permlane32_swap_b32 %0, %1" : "+v"(a0), "+v"(b0));
        asm("v_permlane32_swap_b32 %0, %1" : "+v"(a1), "+v"(b1));
        u32x4 pw;
        pw[0] = a0; pw[1] = a1; pw[2] = b0; pw[3] = b1;
        short8 pf = __builtin_bit_cast(short8, pw);
        const int ks = kg * 2 + hs;
        short8 vf0, vf1;
        {
          int vrow = l31;
          int byte = ((vrow * 128) | (ks * 32 + hf * 16)) ^ ((vrow & 7) << 4);
          vf0 = *(const short8*)(Vbase + byte);
          vrow = 32 + l31;
          byte = ((vrow * 128) | (ks * 32 + hf * 16)) ^ ((vrow & 7) << 4);
          vf1 = *(const short8*)(Vbase + byte);
        }
        __builtin_amdgcn_s_setprio(1);
        o[0] = mfma32(vf0, pf, o[0]);
        o[1] = mfma32(vf1, pf, o[1]);
        __builtin_amdgcn_s_setprio(0);
      }

    asm volatile("s_waitcnt lgkmcnt(0)" ::: "memory");
    __builtin_amdgcn_sched_barrier(0);
    __builtin_amdgcn_s_barrier();
    cur ^= 1;
  }

  // epilogue: combine lane halves, write UNNORMALIZED partial o + l
  float ltot = lrun + __shfl_xor(lrun, 32);

  const int sgb = (isw ? 0 : 2048) + q0;
  if (hf == 0) lbuf[(long)part * 73728 + bh * 2304 + sgb + l31] = ltot;

  float* E = (float*)smem + w * 2048;  // 32q x 64d per wave (wave-private)
#pragma unroll
  for (int mf = 0; mf < 2; ++mf)
#pragma unroll
    for (int rg = 0; rg < 4; ++rg) {
      int d0 = mf * 32 + rg * 8 + hf * 4;
      f32x4 v;
      v[0] = o[mf][rg * 4 + 0];
      v[1] = o[mf][rg * 4 + 1];
      v[2] = o[mf][rg * 4 + 2];
      v[3] = o[mf][rg * 4 + 3];
      *(f32x4*)(E + l31 * 64 + (d0 ^ ((l31 & 7) << 2))) = v;
    }

  float* po = part == 0 ? po0 : (part == 1 ? po1 : po2);
  float* ob = isw ? po + (((long)b * 2048 + q0) * 1024 + head * 64)
                  : po + (long)2 * 2048 * 1024 +
                        (((long)b * 256 + q0) * 1024 + head * 64);
#pragma unroll
  for (int i = 0; i < 8; ++i) {
    int qr = (lane >> 4) + i * 4;
    int dc = (lane & 15) * 4;
    f32x4 v = *(const f32x4*)(E + qr * 64 + (dc ^ ((qr & 7) << 2)));
    *(f32x4*)(ob + (long)qr * 1024 + dc) = v;
  }
}

// ---------------- merge: out = (o0 + o1 + o2) / (l0 + l1 + l2) ----------------
__global__ __launch_bounds__(256) void attn_merge(const float* __restrict__ po0,
                                                  const float* __restrict__ po1,
                                                  const float* __restrict__ po2,
                                                  const float* __restrict__ lbuf,
                                                  float* __restrict__ out) {
  long i = ((long)blockIdx.x * 256 + threadIdx.x) * 4;
  if (i >= 4718592) return;
  int bh, sg;
  if (i < 4194304) {
    int b = (int)(i >> 21), s = (int)((i >> 10) & 2047), h = (int)((i >> 6) & 15);
    bh = b * 16 + h;
    sg = s;
  } else {
    long j = i - 4194304;
    int b = (int)(j >> 18), s = (int)((j >> 10) & 255), h = (int)((j >> 6) & 15);
    bh = b * 16 + h;
    sg = 2048 + s;
  }
  float l0 = lbuf[bh * 2304 + sg];
  float l1 = lbuf[73728 + bh * 2304 + sg];
  float l2 = lbuf[147456 + bh * 2304 + sg];
  f32x4 a = *(const f32x4*)(po0 + i);
  f32x4 c = *(const f32x4*)(po1 + i);
  f32x4 d = *(const f32x4*)(po2 + i);
  float inv = 1.f / (l0 + l1 + l2);
  f32x4 r = (a + c + d) * inv;
  *(f32x4*)(out + i) = r;
}

// ---------------- host ----------------
extern "C" void kernel_launch(void* const* d_in, const int* in_sizes, int n_in,
                              void* d_out, int out_size, void* d_ws, size_t ws_size,
                              hipStream_t stream) {
  (void)in_sizes; (void)n_in; (void)out_size; (void)ws_size;
  const float* word = (const float*)d_in[0];
  const float* ent = (const float*)d_in[1];

  char* ws = (char*)d_ws;
  size_t off = 0;
  auto alloc = [&](size_t bytes) {
    void* p = ws + off;
    off += (bytes + 255) & ~(size_t)255;
    return p;
  };
  // NOTE: po0 aliases [Xw, Xe, Wt) (22.0 MB front region) — those are dead by
  // the time attn_kernel writes po0 (all GEMMs complete first, same stream).
  unsigned short* Xw = (unsigned short*)alloc(4096ull * 1024 * 2);
  unsigned short* Xe = (unsigned short*)alloc(512ull * 1024 * 2);
  unsigned short* Wt[6];
  for (int i = 0; i < 6; ++i) Wt[i] = (unsigned short*)alloc(1024ull * 1024 * 2);
  unsigned short* qw2w = (unsigned short*)alloc(2ull * 16 * 2048 * 64 * 2);
  unsigned short* qw2e = (unsigned short*)alloc(2ull * 16 * 2048 * 64 * 2);
  unsigned short* qe2w = (unsigned short*)alloc(2ull * 16 * 256 * 64 * 2);
  unsigned short* qe2e = (unsigned short*)alloc(2ull * 16 * 256 * 64 * 2);
  unsigned short* Kbuf = (unsigned short*)alloc(2ull * 16 * 2304 * 64 * 2);
  unsigned short* Vtbuf = (unsigned short*)alloc(2ull * 16 * 64 * 2304 * 2);
  float* po1 = (float*)alloc(4718592ull * 4);
  float* po2 = (float*)alloc(4718592ull * 4);
  float* lbuf = (float*)alloc(3ull * 73728 * 4);
  float* po0 = (float*)ws;  // aliases the dead prepass region

  PrepassParams pp;
  pp.sw = word;
  pp.se = ent;
  pp.dw = Xw;
  pp.de = Xe;
  pp.w[0] = (const float*)d_in[2];   // Wq
  pp.w[1] = (const float*)d_in[4];   // Wk
  pp.w[2] = (const float*)d_in[6];   // Wv
  pp.w[3] = (const float*)d_in[8];   // Ww2e
  pp.w[4] = (const float*)d_in[10];  // We2w
  pp.w[5] = (const float*)d_in[12];  // We2e
  for (int i = 0; i < 6; ++i) pp.wt[i] = Wt[i];
  prepass<<<8448, 256, 0, stream>>>(pp);

  const float* bq = (const float*)d_in[3];
  const float* bk = (const float*)d_in[5];
  const float* bv = (const float*)d_in[7];
  const float* bw2e = (const float*)d_in[9];
  const float* be2w = (const float*)d_in[11];
  const float* be2e = (const float*)d_in[13];
  const float qs = 0.125f * 1.44269504f;  // 1/sqrt(64) * log2(e)

  Gemm2Params gp;
  gp.Aw = Xw;
  gp.Ae = Xe;
  gp.job[0] = {Wt[0], bq, qw2w, 2048, 0, 11, 0, qs};
  gp.job[1] = {Wt[3], bw2e, qw2e, 2048, 0, 11, 0, qs};
  gp.job[2] = {Wt[1], bk, Kbuf, 2304, 0, 11, 0, 1.f};
  gp.job[3] = {Wt[2], bv, Vtbuf, 2304, 0, 11, 1, 1.f};
  gp.job[4] = {Wt[4], be2w, qe2w, 256, 0, 8, 0, qs};
  gp.job[5] = {Wt[5], be2e, qe2e, 256, 0, 8, 0, qs};
  gp.job[6] = {Wt[1], bk, Kbuf, 2304, 2048, 8, 0, 1.f};
  gp.job[7] = {Wt[2], bv, Vtbuf, 2304, 2048, 8, 1, 1.f};
  gemm_qkv<<<dim3(8, 36, 4), 256, 0, stream>>>(gp);

  attn_kernel<<<1728, 256, 0, stream>>>(qw2w, qw2e, qe2w, qe2e, Kbuf, Vtbuf,
                                        po0, po1, po2, lbuf);
  attn_merge<<<4608, 256, 0, stream>>>(po0, po1, po2, lbuf, (float*)d_out);
}

// Round 17
// 141.512 us; speedup vs baseline: 1.0281x; 1.0281x over previous
//
#include <hip/hip_runtime.h>
#include <hip/hip_bf16.h>

typedef __attribute__((ext_vector_type(8))) short short8;
typedef __attribute__((ext_vector_type(4))) float f32x4;
typedef __attribute__((ext_vector_type(16))) float f32x16;
typedef __attribute__((ext_vector_type(4))) unsigned short u16x4;
typedef __attribute__((ext_vector_type(8))) unsigned short u16x8;
typedef __attribute__((ext_vector_type(4))) unsigned int u32x4;

__device__ __forceinline__ unsigned short f2b(float f) {
  __hip_bfloat16 h = __float2bfloat16(f);
  return __builtin_bit_cast(unsigned short, h);
}

__device__ __forceinline__ float b2f(unsigned short u) {
  return __builtin_bit_cast(float, (unsigned int)u << 16);
}

__device__ __forceinline__ void gload_lds16(const void* g, void* l) {
  __builtin_amdgcn_global_load_lds(
      (const __attribute__((address_space(1))) unsigned int*)g,
      (__attribute__((address_space(3))) unsigned int*)l, 16, 0, 0);
}

__device__ __forceinline__ f32x16 mfma32(short8 a, short8 b, f32x16 c) {
  return __builtin_amdgcn_mfma_f32_32x32x16_bf16(a, b, c, 0, 0, 0);
}

__device__ __forceinline__ unsigned int cvtpk(float a, float b) {
  unsigned int r;
  asm("v_cvt_pk_bf16_f32 %0, %1, %2" : "=v"(r) : "v"(a), "v"(b));
  return r;
}

// ------- fused prepass: activations f32->bf16 + weight transpose/convert -----
struct PrepassParams {
  const float* sw;
  const float* se;
  unsigned short* dw;
  unsigned short* de;
  const float* w[6];
  unsigned short* wt[6];
};

__global__ __launch_bounds__(256) void prepass(PrepassParams p) {
  const int bx = blockIdx.x;
  const int tid = threadIdx.x;
  if (bx < 2304) {
    int i = bx * 256 + tid;
    const float* s;
    unsigned short* d;
    int j;
    if (i < 524288) {
      s = p.sw; d = p.dw; j = i;
    } else {
      s = p.se; d = p.de; j = i - 524288;
      if (j >= 65536) return;
    }
    const f32x4* sp = (const f32x4*)s;
    f32x4 a = sp[2 * j];
    f32x4 b = sp[2 * j + 1];
    u16x8 o;
    o[0] = f2b(a[0]); o[1] = f2b(a[1]); o[2] = f2b(a[2]); o[3] = f2b(a[3]);
    o[4] = f2b(b[0]); o[5] = f2b(b[1]); o[6] = f2b(b[2]); o[7] = f2b(b[3]);
    ((u16x8*)d)[j] = o;
  } else {
    __shared__ float t[32][33];
    const int idx = bx - 2304;
    const int z = idx >> 10;
    const int rem = idx & 1023;
    const int bxx = rem & 31;
    const int byy = rem >> 5;
    const float* W = p.w[z];
    unsigned short* Wt = p.wt[z];
    const int tx = tid & 31, ty = tid >> 5;
#pragma unroll
    for (int i = 0; i < 4; ++i)
      t[ty + 8 * i][tx] = W[(byy * 32 + ty + 8 * i) * 1024 + bxx * 32 + tx];
    __syncthreads();
#pragma unroll
    for (int i = 0; i < 4; ++i)
      Wt[(bxx * 32 + ty + 8 * i) * 1024 + byy * 32 + tx] = f2b(t[tx][ty + 8 * i]);
  }
}

// ---------------- merged batched projection GEMM ----------------
// Block remap: z (job) varies FASTEST in per-XCD dispatch order so the A-slab
// (256KB) is L2-reused across the 4 jobs before moving to the next row-tile.
struct GemmJob {
  const unsigned short* Wt;  // [1024][1024] bf16, n-major
  const float* bias;
  unsigned short* out;
  int S;
  int s_off;
  int sshift;
  int trans;  // 0: out[bh][s][64]; 1: out[bh][64][2304] (V transposed)
  float scale;
};
struct Gemm2Params {
  const unsigned short* Aw;
  const unsigned short* Ae;
  GemmJob job[8];
};

__global__ __launch_bounds__(256) void gemm_qkv(Gemm2Params p) {
  __shared__ unsigned short smem[16384];
  unsigned short* As = smem;
  unsigned short* Bs = smem + 8192;
  const int tid = threadIdx.x;
  const int w = tid >> 6, lane = tid & 63;
  const int c = lane & 15, g = lane >> 4;
  // L2-locality remap: wid = y + 36*z; consecutive wid per XCD -> z fastest
  const int wid = blockIdx.y + 36 * blockIdx.z;
  const int z = wid & 3;
  const int y = wid >> 2;
  const bool isword = y < 32;
  const GemmJob j = p.job[isword ? z : z + 4];
  const unsigned short* A = isword ? p.Aw : p.Ae;
  const long arow0 = (long)(isword ? y : y - 32) * 128;
  const unsigned short* B = j.Wt;
  const long brow0 = (long)blockIdx.x * 128;

  f32x4 acc[4][4] = {};

  for (int kt = 0; kt < 16; ++kt) {
    __syncthreads();
#pragma unroll
    for (int i = 0; i < 4; ++i) {
      int ch = i * 256 + tid;
      int row = ch >> 3;
      int k8 = ((ch & 7) ^ (row & 7)) << 3;
      const unsigned short* ga = A + (arow0 + row) * 1024 + kt * 64 + k8;
      const unsigned short* gb = B + (brow0 + row) * 1024 + kt * 64 + k8;
      gload_lds16(ga, As + (i * 256 + w * 64) * 8);
      gload_lds16(gb, Bs + (i * 256 + w * 64) * 8);
    }
    __syncthreads();
#pragma unroll
    for (int kf = 0; kf < 2; ++kf) {
      short8 av[4], bv[4];
#pragma unroll
      for (int mf = 0; mf < 4; ++mf) {
        int row = (w >> 1) * 64 + mf * 16 + c;
        int byte = (row * 128 + (kf * 32 + g * 8) * 2) ^ ((row & 7) << 4);
        av[mf] = *(const short8*)((const char*)As + byte);
      }
#pragma unroll
      for (int nf = 0; nf < 4; ++nf) {
        int row = (w & 1) * 64 + nf * 16 + c;
        int byte = (row * 128 + (kf * 32 + g * 8) * 2) ^ ((row & 7) << 4);
        bv[nf] = *(const short8*)((const char*)Bs + byte);
      }
      __builtin_amdgcn_s_setprio(1);
#pragma unroll
      for (int mf = 0; mf < 4; ++mf)
#pragma unroll
        for (int nf = 0; nf < 4; ++nf)
          acc[mf][nf] = __builtin_amdgcn_mfma_f32_16x16x32_bf16(av[mf], bv[nf],
                                                                acc[mf][nf], 0, 0, 0);
      __builtin_amdgcn_s_setprio(0);
    }
  }

  float biasv[4];
#pragma unroll
  for (int nf = 0; nf < 4; ++nf) {
    int n = (int)brow0 + (w & 1) * 64 + nf * 16 + c;
    biasv[nf] = j.bias[n];
  }
  const int smask = (1 << j.sshift) - 1;
  __syncthreads();

  if (j.trans) {
#pragma unroll
    for (int mf = 0; mf < 4; ++mf) {
      int m0 = (w >> 1) * 64 + mf * 16 + g * 4;
#pragma unroll
      for (int nf = 0; nf < 4; ++nf) {
        int n = (w & 1) * 64 + nf * 16 + c;
        u16x4 pv;
#pragma unroll
        for (int r = 0; r < 4; ++r)
          pv[r] = f2b((acc[mf][nf][r] + biasv[nf]) * j.scale);
        int byte = (n * 256 + m0 * 2) ^ ((n & 7) << 4);
        *(u16x4*)((char*)smem + byte) = pv;
      }
    }
    __syncthreads();
#pragma unroll
    for (int i = 0; i < 8; ++i) {
      int ch = i * 256 + tid;
      int nr = ch >> 4, sl = ch & 15;
      int byte = (nr * 256 + sl * 16) ^ ((nr & 7) << 4);
      u16x8 v = *(const u16x8*)((const char*)smem + byte);
      int n = (int)brow0 + nr;
      int hh = n >> 6, dd = n & 63;
      int m = (int)arow0 + sl * 8;
      int b_ = m >> j.sshift;
      int s = (m & smask) + j.s_off;
      *(u16x8*)(j.out + (((long)b_ * 16 + hh) * 64 + dd) * 2304 + s) = v;
    }
  } else {
#pragma unroll
    for (int mf = 0; mf < 4; ++mf) {
#pragma unroll
      for (int r = 0; r < 4; ++r) {
        int m = (w >> 1) * 64 + mf * 16 + g * 4 + r;
#pragma unroll
        for (int nf = 0; nf < 4; ++nf) {
          int n = (w & 1) * 64 + nf * 16 + c;
          unsigned short hv = f2b((acc[mf][nf][r] + biasv[nf]) * j.scale);
          int byte = (m * 256 + n * 2) ^ ((m & 7) << 4);
          *(unsigned short*)((char*)smem + byte) = hv;
        }
      }
    }
    __syncthreads();
#pragma unroll
    for (int i = 0; i < 8; ++i) {
      int ch = i * 256 + tid;
      int mr = ch >> 4, sl = ch & 15;
      int byte = (mr * 256 + sl * 16) ^ ((mr & 7) << 4);
      u16x8 v = *(const u16x8*)((const char*)smem + byte);
      int m = (int)arow0 + mr;
      int b_ = m >> j.sshift;
      int s = (m & smask) + j.s_off;
      int n = (int)brow0 + sl * 8;
      int hh = n >> 6, dd = n & 63;
      *(u16x8*)(j.out + (((long)b_ * 16 + hh) * j.S + s) * 64 + dd) = v;
    }
  }
}

// ---------------- flash attention (key-split x2, bf16 partials) --------------
// 1152 blocks (XCD-grouped), 4 waves x 32 q-rows, part = half of the key range.
// P = exp2(st) unnormalized; scale cancels in merge. Partials stored bf16.
__global__ __launch_bounds__(256) void attn_kernel(
    const unsigned short* __restrict__ qw2w, const unsigned short* __restrict__ qw2e,
    const unsigned short* __restrict__ qe2w, const unsigned short* __restrict__ qe2e,
    const unsigned short* __restrict__ Kg, const unsigned short* __restrict__ Vtg,
    unsigned short* __restrict__ po0, unsigned short* __restrict__ po1,
    float* __restrict__ lbuf) {
  __shared__ unsigned short smem[16384];  // 32 KiB: K dbuf [0,8KB), Vt dbuf [16KB,32KB)

  const int tid = threadIdx.x;
  const int w = tid >> 6, lane = tid & 63;
  const int l31 = lane & 31, hf = lane >> 5;

  // XCD-grouped bijective remap: 1152 = 8 * 144; work = bh*36 + tile*2 + part
  const int flat = blockIdx.x;
  const int work = (flat & 7) * 144 + (flat >> 3);
  const int part = work & 1;
  const int tile = (work % 36) >> 1;
  const int hb = work / 36;
  const int head = hb & 15, b = hb >> 4;

  const bool isw = tile < 16;
  const int Sq = isw ? 2048 : 256;
  const int q0 = (isw ? tile : tile - 16) * 128 + w * 32;
  const int bh = b * 16 + head;
  const unsigned short* Qa =
      (isw ? qw2w : qe2w) + ((long)bh * Sq + q0 + l31) * 64 + hf * 8;
  const unsigned short* Qb =
      (isw ? qw2e : qe2e) + ((long)bh * Sq + q0 + l31) * 64 + hf * 8;
  const unsigned short* Kb = Kg + (long)bh * 2304 * 64;
  const unsigned short* Vtb = Vtg + (long)bh * 64 * 2304;

  short8 qcur[4];
#pragma unroll
  for (int kf = 0; kf < 4; ++kf) qcur[kf] = *(const short8*)(Qa + kf * 16);

  f32x16 o[2] = {};
  float lrun = 0.f;

  auto stage = [&](int t, int bufi) {
    const unsigned short* Kt = Kb + t * 4096;
    unsigned short* Klp = smem + bufi * 4096;
    unsigned short* Vlp = smem + 8192 + bufi * 4096;
#pragma unroll
    for (int i = 0; i < 2; ++i) {
      int ch = i * 256 + tid;
      int row = ch >> 3, c8 = ch & 7;
      int col = (c8 ^ (row & 7)) << 3;
      gload_lds16(Kt + row * 64 + col, Klp + (i * 256 + (tid & 192)) * 8);
      gload_lds16(Vtb + row * 2304 + t * 64 + col, Vlp + (i * 256 + (tid & 192)) * 8);
    }
  };

  const int t0 = part * 18, t1 = t0 + 18;
  stage(t0, 0);
  int cur = 0;

  for (int t = t0; t < t1; ++t) {
    if (t == 32) {  // entity-key region: switch to the *2e query
#pragma unroll
      for (int kf = 0; kf < 4; ++kf) qcur[kf] = *(const short8*)(Qb + kf * 16);
    }
    if (t + 1 < t1) {
      stage(t + 1, cur ^ 1);
      asm volatile("s_waitcnt vmcnt(4)" ::: "memory");
    } else {
      asm volatile("s_waitcnt vmcnt(0)" ::: "memory");
    }
    __builtin_amdgcn_sched_barrier(0);
    __builtin_amdgcn_s_barrier();

    const char* Kbase = (const char*)(smem + cur * 4096);
    const char* Vbase = (const char*)(smem + 8192 + cur * 4096);

    // QK^T: ST[key][q], 2 key-groups of 32
    f32x16 st[2] = {};
#pragma unroll
    for (int kg = 0; kg < 2; ++kg) {
      int row = kg * 32 + l31;
      int rb = (row * 128) | (hf * 16);
      int sw = (row & 7) << 4;
      short8 kfr[4];
#pragma unroll
      for (int kf = 0; kf < 4; ++kf)
        kfr[kf] = *(const short8*)(Kbase + ((rb + kf * 32) ^ sw));
      __builtin_amdgcn_s_setprio(1);
#pragma unroll
      for (int kf = 0; kf < 4; ++kf) st[kg] = mfma32(kfr[kf], qcur[kf], st[kg]);
      __builtin_amdgcn_s_setprio(0);
    }

    // softmax: P = exp2(st), no max subtraction (scale cancels in merge).
    float s0 = 0.f, s1 = 0.f, s2 = 0.f, s3 = 0.f;
#pragma unroll
    for (int kg = 0; kg < 2; ++kg) {
#pragma unroll
      for (int r = 0; r < 16; r += 4) {
        float p0 = __builtin_amdgcn_exp2f(st[kg][r + 0]);
        float p1 = __builtin_amdgcn_exp2f(st[kg][r + 1]);
        float p2 = __builtin_amdgcn_exp2f(st[kg][r + 2]);
        float p3 = __builtin_amdgcn_exp2f(st[kg][r + 3]);
        st[kg][r + 0] = p0; st[kg][r + 1] = p1;
        st[kg][r + 2] = p2; st[kg][r + 3] = p3;
        s0 += p0; s1 += p1; s2 += p2; s3 += p3;
      }
    }
    lrun += (s0 + s1) + (s2 + s3);

    // P -> bf16 B-frags in-register (cvt_pk + permlane32_swap), PV accumulate
#pragma unroll
    for (int kg = 0; kg < 2; ++kg)
#pragma unroll
      for (int hs = 0; hs < 2; ++hs) {
        const int rbase = hs * 8;
        unsigned int a0 = cvtpk(st[kg][rbase + 0], st[kg][rbase + 1]);
        unsigned int a1 = cvtpk(st[kg][rbase + 2], st[kg][rbase + 3]);
        unsigned int b0 = cvtpk(st[kg][rbase + 4], st[kg][rbase + 5]);
        unsigned int b1 = cvtpk(st[kg][rbase + 6], st[kg][rbase + 7]);
        asm("v_permlane32_swap_b32 %0, %1" : "+v"(a0), "+v"(b0));
        asm("v_permlane32_swap_b32 %0, %1" : "+v"(a1), "+v"(b1));
        u32x4 pw;
        pw[0] = a0; pw[1] = a1; pw[2] = b0; pw[3] = b1;
        short8 pf = __builtin_bit_cast(short8, pw);
        const int ks = kg * 2 + hs;
        short8 vf0, vf1;
        {
          int vrow = l31;
          int byte = ((vrow * 128) | (ks * 32 + hf * 16)) ^ ((vrow & 7) << 4);
          vf0 = *(const short8*)(Vbase + byte);
          vrow = 32 + l31;
          byte = ((vrow * 128) | (ks * 32 + hf * 16)) ^ ((vrow & 7) << 4);
          vf1 = *(const short8*)(Vbase + byte);
        }
        __builtin_amdgcn_s_setprio(1);
        o[0] = mfma32(vf0, pf, o[0]);
        o[1] = mfma32(vf1, pf, o[1]);
        __builtin_amdgcn_s_setprio(0);
      }

    asm volatile("s_waitcnt lgkmcnt(0)" ::: "memory");
    __builtin_amdgcn_sched_barrier(0);
    __builtin_amdgcn_s_barrier();
    cur ^= 1;
  }

  // epilogue: combine lane halves, write UNNORMALIZED bf16 partial o + f32 l
  float ltot = lrun + __shfl_xor(lrun, 32);

  const int sgb = (isw ? 0 : 2048) + q0;
  if (hf == 0) lbuf[(long)part * 73728 + bh * 2304 + sgb + l31] = ltot;

  float* E = (float*)smem + w * 2048;  // 32q x 64d per wave (wave-private)
#pragma unroll
  for (int mf = 0; mf < 2; ++mf)
#pragma unroll
    for (int rg = 0; rg < 4; ++rg) {
      int d0 = mf * 32 + rg * 8 + hf * 4;
      f32x4 v;
      v[0] = o[mf][rg * 4 + 0];
      v[1] = o[mf][rg * 4 + 1];
      v[2] = o[mf][rg * 4 + 2];
      v[3] = o[mf][rg * 4 + 3];
      *(f32x4*)(E + l31 * 64 + (d0 ^ ((l31 & 7) << 2))) = v;
    }

  unsigned short* po = part ? po1 : po0;
  unsigned short* ob = isw
      ? po + (((long)b * 2048 + q0) * 1024 + head * 64)
      : po + (long)2 * 2048 * 1024 + (((long)b * 256 + q0) * 1024 + head * 64);
#pragma unroll
  for (int i = 0; i < 4; ++i) {
    int qr = (lane >> 3) + i * 8;
    int dcg = (lane & 7) * 8;
    int sw = (qr & 7) << 2;
    f32x4 v0 = *(const f32x4*)(E + qr * 64 + (dcg ^ sw));
    f32x4 v1 = *(const f32x4*)(E + qr * 64 + ((dcg + 4) ^ sw));
    u32x4 pk;
    pk[0] = cvtpk(v0[0], v0[1]);
    pk[1] = cvtpk(v0[2], v0[3]);
    pk[2] = cvtpk(v1[0], v1[1]);
    pk[3] = cvtpk(v1[2], v1[3]);
    *(u32x4*)(ob + (long)qr * 1024 + dcg) = pk;
  }
}

// ---------------- merge: out = (o0 + o1) / (l0 + l1), bf16 partials ----------
__global__ __launch_bounds__(256) void attn_merge(
    const unsigned short* __restrict__ po0, const unsigned short* __restrict__ po1,
    const float* __restrict__ lbuf, float* __restrict__ out) {
  long i = ((long)blockIdx.x * 256 + threadIdx.x) * 4;
  if (i >= 4718592) return;
  int bh, sg;
  if (i < 4194304) {
    int b = (int)(i >> 21), s = (int)((i >> 10) & 2047), h = (int)((i >> 6) & 15);
    bh = b * 16 + h;
    sg = s;
  } else {
    long j = i - 4194304;
    int b = (int)(j >> 18), s = (int)((j >> 10) & 255), h = (int)((j >> 6) & 15);
    bh = b * 16 + h;
    sg = 2048 + s;
  }
  float l0 = lbuf[bh * 2304 + sg];
  float l1 = lbuf[73728 + bh * 2304 + sg];
  u16x4 a4 = *(const u16x4*)(po0 + i);
  u16x4 c4 = *(const u16x4*)(po1 + i);
  float inv = 1.f / (l0 + l1);
  f32x4 r;
#pragma unroll
  for (int k = 0; k < 4; ++k) r[k] = (b2f(a4[k]) + b2f(c4[k])) * inv;
  *(f32x4*)(out + i) = r;
}

// ---------------- host ----------------
extern "C" void kernel_launch(void* const* d_in, const int* in_sizes, int n_in,
                              void* d_out, int out_size, void* d_ws, size_t ws_size,
                              hipStream_t stream) {
  (void)in_sizes; (void)n_in; (void)out_size; (void)ws_size;
  const float* word = (const float*)d_in[0];
  const float* ent = (const float*)d_in[1];

  char* ws = (char*)d_ws;
  size_t off = 0;
  auto alloc = [&](size_t bytes) {
    void* p = ws + off;
    off += (bytes + 255) & ~(size_t)255;
    return p;
  };
  // NOTE: po0 aliases [Xw, Xe, Wt) (22.0 MB front region) — those are dead by
  // the time attn_kernel writes po0 (all GEMMs complete first, same stream).
  unsigned short* Xw = (unsigned short*)alloc(4096ull * 1024 * 2);
  unsigned short* Xe = (unsigned short*)alloc(512ull * 1024 * 2);
  unsigned short* Wt[6];
  for (int i = 0; i < 6; ++i) Wt[i] = (unsigned short*)alloc(1024ull * 1024 * 2);
  unsigned short* qw2w = (unsigned short*)alloc(2ull * 16 * 2048 * 64 * 2);
  unsigned short* qw2e = (unsigned short*)alloc(2ull * 16 * 2048 * 64 * 2);
  unsigned short* qe2w = (unsigned short*)alloc(2ull * 16 * 256 * 64 * 2);
  unsigned short* qe2e = (unsigned short*)alloc(2ull * 16 * 256 * 64 * 2);
  unsigned short* Kbuf = (unsigned short*)alloc(2ull * 16 * 2304 * 64 * 2);
  unsigned short* Vtbuf = (unsigned short*)alloc(2ull * 16 * 64 * 2304 * 2);
  unsigned short* po1 = (unsigned short*)alloc(4718592ull * 2);
  float* lbuf = (float*)alloc(2ull * 73728 * 4);
  unsigned short* po0 = (unsigned short*)ws;  // aliases dead prepass region (9.4MB)

  PrepassParams pp;
  pp.sw = word;
  pp.se = ent;
  pp.dw = Xw;
  pp.de = Xe;
  pp.w[0] = (const float*)d_in[2];   // Wq
  pp.w[1] = (const float*)d_in[4];   // Wk
  pp.w[2] = (const float*)d_in[6];   // Wv
  pp.w[3] = (const float*)d_in[8];   // Ww2e
  pp.w[4] = (const float*)d_in[10];  // We2w
  pp.w[5] = (const float*)d_in[12];  // We2e
  for (int i = 0; i < 6; ++i) pp.wt[i] = Wt[i];
  prepass<<<8448, 256, 0, stream>>>(pp);

  const float* bq = (const float*)d_in[3];
  const float* bk = (const float*)d_in[5];
  const float* bv = (const float*)d_in[7];
  const float* bw2e = (const float*)d_in[9];
  const float* be2w = (const float*)d_in[11];
  const float* be2e = (const float*)d_in[13];
  const float qs = 0.125f * 1.44269504f;  // 1/sqrt(64) * log2(e)

  Gemm2Params gp;
  gp.Aw = Xw;
  gp.Ae = Xe;
  gp.job[0] = {Wt[0], bq, qw2w, 2048, 0, 11, 0, qs};
  gp.job[1] = {Wt[3], bw2e, qw2e, 2048, 0, 11, 0, qs};
  gp.job[2] = {Wt[1], bk, Kbuf, 2304, 0, 11, 0, 1.f};
  gp.job[3] = {Wt[2], bv, Vtbuf, 2304, 0, 11, 1, 1.f};
  gp.job[4] = {Wt[4], be2w, qe2w, 256, 0, 8, 0, qs};
  gp.job[5] = {Wt[5], be2e, qe2e, 256, 0, 8, 0, qs};
  gp.job[6] = {Wt[1], bk, Kbuf, 2304, 2048, 8, 0, 1.f};
  gp.job[7] = {Wt[2], bv, Vtbuf, 2304, 2048, 8, 1, 1.f};
  gemm_qkv<<<dim3(8, 36, 4), 256, 0, stream>>>(gp);

  attn_kernel<<<1152, 256, 0, stream>>>(qw2w, qw2e, qe2w, qe2e, Kbuf, Vtbuf,
                                        po0, po1, lbuf);
  attn_merge<<<4608, 256, 0, stream>>>(po0, po1, lbuf, (float*)d_out);
}